// Round 6
// baseline (251.928 us; speedup 1.0000x reference)
//
#include <hip/hip_runtime.h>
#include <hip/hip_bf16.h>

// CausalAttention: B=4, S=2048, d=1024, single head, causal. fp32 I/O, bf16 MFMA inside.
//
// R14: visibility round. Accounting says scores+PV burn ~110 us (3-5x their work
//      estimate at QKV's 798 TF rate) but they have NEVER appeared in top-5 -- every
//      QKV dispatch (65 us) outranks them. Split QKV into 3 dispatches (Q,K,V; each
//      grid 8x64 = 512 blocks = 2.0 exact rounds, ~22 us) so scores (MODE 1) and
//      PV (MODE 2) surface in top-5 with full counters next round. Side benefit:
//      per-dispatch B working set 6.3 MB -> 2.1 MB, fits the 4 MB per-XCD L2
//      (fused QKV's per-XCD Wt footprint was all three matrices -> guaranteed B
//      misses). Xb re-read 3x but L3-resident. Kernel body untouched.
//
// Pipeline:
//   1) Wq/Wk/Wv fp32 -> bf16 transposed, stacked Wt [3072][1024]
//   2) x fp32 -> bf16 Xb
//   3) Q = Xb*Wq^T; K = Xb*Wk^T; V = Xb*Wv^T  (MODE 3, 128^2, 3 x grid 8x64)
//   4) Vt = V^T per batch + zero rowsum (fused)
//   5) E = masked-exp(Q*K^T/32), rowsum accumulated   (MODE 1, 128^2, flat tri grid 544)
//   6) out(fp32) = (E * V) / rowsum                   (MODE 2, 128^2, balanced flat 512)

typedef __bf16 bf16_t;
typedef __bf16 bf16x8 __attribute__((ext_vector_type(8)));
typedef float f32x4 __attribute__((ext_vector_type(4)));

__device__ __forceinline__ void load_lds16(const bf16_t* g, bf16_t* l) {
  __builtin_amdgcn_global_load_lds(
      (__attribute__((address_space(1))) void*)(void*)g,
      (__attribute__((address_space(3))) void*)l,
      16, 0, 0);
}

// C[m][n] = sum_k A[m][k]*B[n][k]  (A:[M][K], B:[N][K] row-major bf16)
// MODE: 1 scores: flat triangular grid, epilogue mask+exp+rowsum
//       2 pv: balanced flat grid, clamp K at rowBase+BMv, epilogue scale by 1/rowsum
//       3 plain gemm (per-matrix QKV projection)
// LDS swizzle: 16B chunk position p of row r holds global chunk p ^ (r&7);
// fragment reads hit all 32 banks 2-way (free, m136). Conflicts measured 0 (R5-R13).
template <int BMv, int BNv, int NW, int MODE, typename OT>
__global__ __launch_bounds__(NW * 64)
void gemm_nt_bf16(const bf16_t* __restrict__ A, const bf16_t* __restrict__ B,
                  OT* __restrict__ C0,
                  float* __restrict__ RS,
                  int M, int K, int ldc,
                  long strideA, long strideB, long strideC)
{
  constexpr int MW = BMv / 64;       // wave grid: MW x (NW/MW)
  constexpr int RA = BMv / NW;       // rows staged per wave (A)
  constexpr int RB = BNv / NW;       // rows staged per wave (B)

  int bx, by, bz;
  if constexpr (MODE == 1) {
    // Flat XCD-balanced lower-triangle enumeration (S=2048, 128-tiles, 16 panels/batch).
    // XCD x (= blockIdx.x & 7, m09 round-robin) owns panels {x, 15-x} of every batch:
    // weight (x+1) + (16-x) = 17 tiles per batch -> 68 per XCD, exact balance.
    const int f = blockIdx.x;          // 544 blocks
    const int x = f & 7;
    const int j = f >> 3;              // [0, 68)
    bz = j / 17;
    const int r = j % 17;
    by = (r <= x) ? x : 15 - x;
    bx = (r <= x) ? r : r - (x + 1);
  } else if constexpr (MODE == 2) {
    // PV balanced flat grid: 512 blocks. rank r = f>>5 maps to by so that the
    // co-resident pair (f, f+256) costs (16-r) + (r+1) = 17 K-units on every CU.
    // XCD = f&7 = bx: each XCD stages one 128-col Vt panel (2 MB total, L2-fits).
    const int f = blockIdx.x;
    const int rank = f >> 5;           // [0,16)
    const int w = f & 31;
    by = (rank < 8) ? (15 - rank) : (rank - 8);
    bx = w & 7;
    bz = w >> 3;
  } else {
    // XCD-aware remap: pin all x-blocks of an A-panel (y,z) to one XCD.
    // Requires (gridDim.y*gridDim.z) % 8 == 0 -- true here (64).
    const int gx = gridDim.x, gy = gridDim.y;
    const int NP = gy * gridDim.z;
    const int P  = NP >> 3;                         // panels per XCD
    const int flat = blockIdx.x + gx * (blockIdx.y + gy * blockIdx.z);
    const int xcd  = flat & 7;
    const int i    = flat >> 3;
    const int pan  = xcd * P + (i % P);
    bx = i / P;
    by = pan % gy;
    bz = pan / gy;
  }

  const int rowBase = by * BMv;
  const int colBase = bx * BNv;

  __shared__ __align__(16) bf16_t sA[BMv * 64];
  __shared__ __align__(16) bf16_t sB[BNv * 64];

  A += (size_t)bz * strideA;
  B += (size_t)bz * strideB;
  float* rs_b = RS + (size_t)bz * 2048;

  const int tid  = threadIdx.x;
  const int wave = tid >> 6;
  const int lane = tid & 63;
  const int quad = lane >> 4;
  const int ln16 = lane & 15;

  const int wm = (wave % MW) * 64;
  const int wn = (wave / MW) * 64;

  const int rA = lane >> 3;                       // 0..7 row-in-group
  const int sColOff = ((lane & 7) ^ rA) * 8;      // swizzled chunk offset (elems)
  const bf16_t* pA = A + (size_t)(rowBase + wave * RA + rA) * K + sColOff;
  const bf16_t* pB = B + (size_t)(colBase + wave * RB + rA) * K + sColOff;
  bf16_t* ldsA = sA + wave * RA * 64;
  bf16_t* ldsB = sB + wave * RB * 64;

  f32x4 acc[4][4] = {};

  const int Kend = (MODE == 2) ? (K < rowBase + BMv ? K : rowBase + BMv) : K;

  for (int k0 = 0; k0 < Kend; k0 += 64) {
#pragma unroll
    for (int j = 0; j < RA / 8; j++)
      load_lds16(pA + k0 + (size_t)(8 * j) * K, ldsA + j * 512);
#pragma unroll
    for (int j = 0; j < RB / 8; j++)
      load_lds16(pB + k0 + (size_t)(8 * j) * K, ldsB + j * 512);
    __syncthreads();   // drains vmcnt for all waves

#pragma unroll
    for (int kk = 0; kk < 2; kk++) {
      bf16x8 af[4], bfr[4];
#pragma unroll
      for (int mt = 0; mt < 4; mt++) {
        const int row = wm + mt * 16 + ln16;
        af[mt] = *(const bf16x8*)(sA + row * 64 + (((kk * 4 + quad) ^ (row & 7)) * 8));
      }
#pragma unroll
      for (int nt = 0; nt < 4; nt++) {
        const int row = wn + nt * 16 + ln16;
        bfr[nt] = *(const bf16x8*)(sB + row * 64 + (((kk * 4 + quad) ^ (row & 7)) * 8));
      }
#pragma unroll
      for (int mt = 0; mt < 4; mt++)
#pragma unroll
        for (int nt = 0; nt < 4; nt++)
          acc[mt][nt] = __builtin_amdgcn_mfma_f32_16x16x32_bf16(af[mt], bfr[nt], acc[mt][nt], 0, 0, 0);
    }
    __syncthreads();
  }

  OT* Cw = C0 + (size_t)bz * strideC;
  const int cb = colBase;

  // epilogue: C/D layout col = lane&15, row = quad*4 + r  [measured m89/m91]
#pragma unroll
  for (int mt = 0; mt < 4; mt++) {
#pragma unroll
    for (int r = 0; r < 4; r++) {
      const int row = rowBase + wm + mt * 16 + quad * 4 + r;
      float rsum = 0.0f;
      float rinv = 1.0f;
      if (MODE == 2) rinv = 1.0f / rs_b[row];
#pragma unroll
      for (int nt = 0; nt < 4; nt++) {
        const int col = cb + wn + nt * 16 + ln16;
        float v = acc[mt][nt][r];
        if (MODE == 1) {
          const float e = (col <= row) ? __expf(v * 0.03125f) : 0.0f;  // s/sqrt(1024)
          rsum += e;
          v = e;
        } else if (MODE == 2) {
          v *= rinv;
        }
        Cw[(size_t)row * ldc + col] = (OT)v;
      }
      if (MODE == 1) {
        rsum += __shfl_xor(rsum, 1, 64);
        rsum += __shfl_xor(rsum, 2, 64);
        rsum += __shfl_xor(rsum, 4, 64);
        rsum += __shfl_xor(rsum, 8, 64);
        if (ln16 == 0) atomicAdd(rs_b + row, rsum);
      }
    }
  }
}

// three fp32 [D][D] -> bf16 transposed, stacked [3D][D]; z selects source
__global__ __launch_bounds__(256)
void transpose_cvt3(const float* __restrict__ w0, const float* __restrict__ w1,
                    const float* __restrict__ w2, bf16_t* __restrict__ out, int D)
{
  const float* in = (blockIdx.z == 0) ? w0 : (blockIdx.z == 1) ? w1 : w2;
  bf16_t* o = out + (size_t)blockIdx.z * D * D;
  __shared__ float tile[32][33];
  const int c0 = blockIdx.x * 32, r0 = blockIdx.y * 32;
  const int tx = threadIdx.x, ty = threadIdx.y;  // (32, 8)
#pragma unroll
  for (int i = 0; i < 32; i += 8)
    tile[ty + i][tx] = in[(size_t)(r0 + ty + i) * D + (c0 + tx)];
  __syncthreads();
#pragma unroll
  for (int i = 0; i < 32; i += 8)
    o[(size_t)(c0 + ty + i) * D + (r0 + tx)] = (bf16_t)tile[tx][ty + i];
}

// bf16 [R][C] -> bf16 transposed [C][R]; batched via blockIdx.z.
// Block (0,0,0) additionally zeroes the rowsum buffer (disjoint memory; its only
// consumer is the subsequent scores launch on the same stream).
__global__ __launch_bounds__(256)
void transpose16z(const unsigned short* __restrict__ in, unsigned short* __restrict__ out,
                  int R, int C, float* __restrict__ z, int nz)
{
  __shared__ unsigned short tile[32][33];
  const size_t bo = (size_t)blockIdx.z * R * C;
  const int c0 = blockIdx.x * 32, r0 = blockIdx.y * 32;
  const int tx = threadIdx.x, ty = threadIdx.y;  // (32, 8)
  if (blockIdx.x == 0 && blockIdx.y == 0 && blockIdx.z == 0) {
    const int t = ty * 32 + tx;
    for (int i = t; i < nz; i += 256) z[i] = 0.0f;
  }
#pragma unroll
  for (int i = 0; i < 32; i += 8)
    tile[ty + i][tx] = in[bo + (size_t)(r0 + ty + i) * C + (c0 + tx)];
  __syncthreads();
#pragma unroll
  for (int i = 0; i < 32; i += 8)
    out[bo + (size_t)(c0 + ty + i) * R + (r0 + tx)] = tile[tx][ty + i];
}

// fp32 -> bf16 elementwise, 8/thread, vector load+store
__global__ __launch_bounds__(256)
void cvt_f32_bf16(const float* __restrict__ in, bf16_t* __restrict__ out, long n)
{
  long i = ((long)blockIdx.x * 256 + threadIdx.x) * 8;
  if (i + 7 < n) {
    float4 a = *(const float4*)(in + i);
    float4 b = *(const float4*)(in + i + 4);
    bf16x8 o;
    o[0] = (bf16_t)a.x; o[1] = (bf16_t)a.y; o[2] = (bf16_t)a.z; o[3] = (bf16_t)a.w;
    o[4] = (bf16_t)b.x; o[5] = (bf16_t)b.y; o[6] = (bf16_t)b.z; o[7] = (bf16_t)b.w;
    *(bf16x8*)(out + i) = o;
  }
}

extern "C" void kernel_launch(void* const* d_in, const int* in_sizes, int n_in,
                              void* d_out, int out_size, void* d_ws, size_t ws_size,
                              hipStream_t stream) {
  const float* x  = (const float*)d_in[0];
  const float* Wq = (const float*)d_in[1];
  const float* Wk = (const float*)d_in[2];
  const float* Wv = (const float*)d_in[3];
  float* out = (float*)d_out;

  const int Bb = 4, S = 2048, D = 1024;
  const int M = Bb * S;  // 8192

  // ws (bf16 elems): Q | K | Vt | Wt(3*D*D) | Xb | V   = 90,177,536 B (proven fit)
  // Sc (Bb*S*S == 2*M*D) aliases [Xb|V]; rowsum (32 KB f32) reuses Wt (dead post-QKV).
  bf16_t* ws = (bf16_t*)d_ws;
  bf16_t* Q   = ws;
  bf16_t* Kp  = Q  + (size_t)M * D;
  bf16_t* Vt  = Kp + (size_t)M * D;
  bf16_t* Wt  = Vt + (size_t)M * D;          // [3072][1024] stacked
  bf16_t* Xb  = Wt + 3 * (size_t)D * D;
  bf16_t* V   = Xb + (size_t)M * D;
  bf16_t* Sc  = Xb;
  float*  rowsum = (float*)Wt;               // Bb*S floats

  const dim3 tb(32, 8);

  // 1) W fp32 -> bf16 transposed, stacked
  transpose_cvt3<<<dim3(D / 32, D / 32, 3), tb, 0, stream>>>(Wq, Wk, Wv, Wt, D);

  // 2) x -> bf16
  cvt_f32_bf16<<<dim3((M * D) / (256 * 8)), dim3(256), 0, stream>>>(x, Xb, (long)M * D);

  // 3) projections, one dispatch per matrix (512 blocks = 2.0 rounds each;
  //    B = one 2.1 MB Wt matrix -> per-XCD L2-resident)
  gemm_nt_bf16<128, 128, 4, 3, bf16_t><<<dim3(D / 128, M / 128, 1), dim3(256), 0, stream>>>(
      Xb, Wt,             Q,  rowsum, M, D, D, 0, 0, 0);
  gemm_nt_bf16<128, 128, 4, 3, bf16_t><<<dim3(D / 128, M / 128, 1), dim3(256), 0, stream>>>(
      Xb, Wt + (size_t)D * D,     Kp, rowsum, M, D, D, 0, 0, 0);
  gemm_nt_bf16<128, 128, 4, 3, bf16_t><<<dim3(D / 128, M / 128, 1), dim3(256), 0, stream>>>(
      Xb, Wt + 2 * (size_t)D * D, V,  rowsum, M, D, D, 0, 0, 0);

  // 4) Vt per batch + zero rowsum (Wt dead now; fused into one dispatch)
  transpose16z<<<dim3(D / 32, S / 32, Bb), tb, 0, stream>>>(
      (const unsigned short*)V, (unsigned short*)Vt, S, D, rowsum, M);

  // 5) E = masked-exp(Q*K^T/32) + rowsum  (flat triangular grid: 544 tiles, 68/XCD exact)
  gemm_nt_bf16<128, 128, 4, 1, bf16_t><<<dim3(544, 1, 1), dim3(256), 0, stream>>>(
      Q, Kp, Sc, rowsum, S, D, S, (long)S * D, (long)S * D, (long)S * S);

  // 6) out(fp32) = (E*V)/rowsum  (balanced flat grid: 512 blocks, 17 K-units per CU pair)
  gemm_nt_bf16<128, 128, 4, 2, float><<<dim3(512, 1, 1), dim3(256), 0, stream>>>(
      Sc, Vt, out, rowsum, S, S, D, (long)S * S, (long)D * S, (long)S * D);
}

// Round 7
// 237.669 us; speedup vs baseline: 1.0600x; 1.0600x over previous
//
#include <hip/hip_runtime.h>
#include <hip/hip_bf16.h>

// CausalAttention: B=4, S=2048, d=1024, single head, causal. fp32 I/O, bf16 MFMA inside.
//
// R15: PV fetch fix + QKV revert.
//      R14 made PV visible: 46 us, FETCH 78 MB vs ~34 compulsory, MfmaUtil 14%,
//      occupancy 12%. Cause: MODE-2 map had XCD = bx, so the 8 col-blocks sharing an
//      E row-panel (A operand) sat on 8 DIFFERENT XCDs -> each XCD re-fetched every
//      panel (~8x17 MB with partial reuse = 78 MB). Same disease R8 cured for QKV.
//      (a) PV map now pins all 8 col-blocks of a panel to ONE XCD (bx fastest),
//          heavy-first panel order, 4 (heavy,light) pairs per XCD = exactly 68
//          K-units each; co-resident pair (i,i+32) = 17 units on every CU.
//          Per-XCD A footprint ~2.2 MB -> L2-resident.
//      (b) QKV reverts to the fused single dispatch (24x64 grid; 64.6-65.2 us
//          measured in R12/R13; the 3-way split cost ~15 us total in R14).
//
// Pipeline:
//   1) Wq/Wk/Wv fp32 -> bf16 transposed, stacked Wt [3072][1024]
//   2) x fp32 -> bf16 Xb
//   3) {Q,K,V} = Xb * Wt^T       (MODE 3, 128^2, grid 24x64)
//   4) Vt = V^T per batch + zero rowsum (fused)
//   5) E = masked-exp(Q*K^T/32), rowsum accumulated   (MODE 1, 128^2, flat tri grid 544)
//   6) out(fp32) = (E * V) / rowsum                   (MODE 2, 128^2, panel-pinned 512)

typedef __bf16 bf16_t;
typedef __bf16 bf16x8 __attribute__((ext_vector_type(8)));
typedef float f32x4 __attribute__((ext_vector_type(4)));

__device__ __forceinline__ void load_lds16(const bf16_t* g, bf16_t* l) {
  __builtin_amdgcn_global_load_lds(
      (__attribute__((address_space(1))) void*)(void*)g,
      (__attribute__((address_space(3))) void*)l,
      16, 0, 0);
}

// C[m][n] = sum_k A[m][k]*B[n][k]  (A:[M][K], B:[N][K] row-major bf16)
// MODE: 1 scores: flat triangular grid, epilogue mask+exp+rowsum
//       2 pv: panel-pinned flat grid, clamp K at rowBase+BMv, epilogue 1/rowsum
//       3 fused qkv split
// LDS swizzle: 16B chunk position p of row r holds global chunk p ^ (r&7);
// fragment reads hit all 32 banks 2-way (free, m136). Conflicts measured 0 (R5-R14).
template <int BMv, int BNv, int NW, int MODE, typename OT>
__global__ __launch_bounds__(NW * 64)
void gemm_nt_bf16(const bf16_t* __restrict__ A, const bf16_t* __restrict__ B,
                  OT* __restrict__ C0, OT* __restrict__ C1, OT* __restrict__ C2,
                  float* __restrict__ RS,
                  int M, int K, int ldc,
                  long strideA, long strideB, long strideC)
{
  constexpr int MW = BMv / 64;       // wave grid: MW x (NW/MW)
  constexpr int RA = BMv / NW;       // rows staged per wave (A)
  constexpr int RB = BNv / NW;       // rows staged per wave (B)

  int bx, by, bz;
  if constexpr (MODE == 1) {
    // Flat XCD-balanced lower-triangle enumeration (S=2048, 128-tiles, 16 panels/batch).
    // XCD x (= blockIdx.x & 7, m09 round-robin) owns panels {x, 15-x} of every batch:
    // weight (x+1) + (16-x) = 17 tiles per batch -> 68 per XCD, exact balance.
    const int f = blockIdx.x;          // 544 blocks
    const int x = f & 7;
    const int j = f >> 3;              // [0, 68)
    bz = j / 17;
    const int r = j % 17;
    by = (r <= x) ? x : 15 - x;
    bx = (r <= x) ? r : r - (x + 1);
  } else if constexpr (MODE == 2) {
    // PV panel-pinned flat grid: 512 blocks. XCD = f&7 owns 8 E row-panels
    // (4 heavy-first (by=15-pr, then light by=pr) pairs; cost (16-pr)+(pr+1)=17
    // per pair -> 68 K-units per XCD exactly). bx fastest: the 8 col-blocks of a
    // panel are consecutive ON ONE XCD -> A-panel fetched once, ~2.2 MB/XCD in L2.
    // Co-resident pair (i, i+32) = heavy_j + light_j = 17 units on every CU.
    const int f  = blockIdx.x;
    const int xcd = f & 7;
    const int i  = f >> 3;             // [0,64) within XCD
    bx = i & 7;
    const int p  = i >> 3;             // [0,8) panel slot
    const int j  = p & 3;              // pair index
    const int heavy = (p < 4);         // heavy panels first
    const int g  = xcd * 4 + j;        // [0,32) global (bz,pr) pair
    bz = g >> 3;
    const int pr = g & 7;
    by = heavy ? (15 - pr) : pr;
  } else {
    // XCD-aware remap: pin all x-blocks of an A-panel (y,z) to one XCD.
    // Requires (gridDim.y*gridDim.z) % 8 == 0 -- true here (64).
    const int gx = gridDim.x, gy = gridDim.y;
    const int NP = gy * gridDim.z;
    const int P  = NP >> 3;                         // panels per XCD
    const int flat = blockIdx.x + gx * (blockIdx.y + gy * blockIdx.z);
    const int xcd  = flat & 7;
    const int i    = flat >> 3;
    const int pan  = xcd * P + (i % P);
    bx = i / P;
    by = pan % gy;
    bz = pan / gy;
  }

  const int rowBase = by * BMv;
  const int colBase = bx * BNv;

  __shared__ __align__(16) bf16_t sA[BMv * 64];
  __shared__ __align__(16) bf16_t sB[BNv * 64];

  A += (size_t)bz * strideA;
  B += (size_t)bz * strideB;
  float* rs_b = RS + (size_t)bz * 2048;

  const int tid  = threadIdx.x;
  const int wave = tid >> 6;
  const int lane = tid & 63;
  const int quad = lane >> 4;
  const int ln16 = lane & 15;

  const int wm = (wave % MW) * 64;
  const int wn = (wave / MW) * 64;

  const int rA = lane >> 3;                       // 0..7 row-in-group
  const int sColOff = ((lane & 7) ^ rA) * 8;      // swizzled chunk offset (elems)
  const bf16_t* pA = A + (size_t)(rowBase + wave * RA + rA) * K + sColOff;
  const bf16_t* pB = B + (size_t)(colBase + wave * RB + rA) * K + sColOff;
  bf16_t* ldsA = sA + wave * RA * 64;
  bf16_t* ldsB = sB + wave * RB * 64;

  f32x4 acc[4][4] = {};

  const int Kend = (MODE == 2) ? (K < rowBase + BMv ? K : rowBase + BMv) : K;

  for (int k0 = 0; k0 < Kend; k0 += 64) {
#pragma unroll
    for (int j = 0; j < RA / 8; j++)
      load_lds16(pA + k0 + (size_t)(8 * j) * K, ldsA + j * 512);
#pragma unroll
    for (int j = 0; j < RB / 8; j++)
      load_lds16(pB + k0 + (size_t)(8 * j) * K, ldsB + j * 512);
    __syncthreads();   // drains vmcnt for all waves

#pragma unroll
    for (int kk = 0; kk < 2; kk++) {
      bf16x8 af[4], bfr[4];
#pragma unroll
      for (int mt = 0; mt < 4; mt++) {
        const int row = wm + mt * 16 + ln16;
        af[mt] = *(const bf16x8*)(sA + row * 64 + (((kk * 4 + quad) ^ (row & 7)) * 8));
      }
#pragma unroll
      for (int nt = 0; nt < 4; nt++) {
        const int row = wn + nt * 16 + ln16;
        bfr[nt] = *(const bf16x8*)(sB + row * 64 + (((kk * 4 + quad) ^ (row & 7)) * 8));
      }
#pragma unroll
      for (int mt = 0; mt < 4; mt++)
#pragma unroll
        for (int nt = 0; nt < 4; nt++)
          acc[mt][nt] = __builtin_amdgcn_mfma_f32_16x16x32_bf16(af[mt], bfr[nt], acc[mt][nt], 0, 0, 0);
    }
    __syncthreads();
  }

  // output target: MODE 3 splits by 1024-col groups (uniform per block)
  OT* Cw = C0;
  int cb = colBase;
  if constexpr (MODE == 3) {
    const int which = colBase >> 10;               // 128-col tiles never span matrices
    Cw = (which == 0) ? C0 : (which == 1) ? C1 : C2;
    cb = colBase & 1023;
  }
  Cw += (size_t)bz * strideC;

  // epilogue: C/D layout col = lane&15, row = quad*4 + r  [measured m89/m91]
#pragma unroll
  for (int mt = 0; mt < 4; mt++) {
#pragma unroll
    for (int r = 0; r < 4; r++) {
      const int row = rowBase + wm + mt * 16 + quad * 4 + r;
      float rsum = 0.0f;
      float rinv = 1.0f;
      if (MODE == 2) rinv = 1.0f / rs_b[row];
#pragma unroll
      for (int nt = 0; nt < 4; nt++) {
        const int col = cb + wn + nt * 16 + ln16;
        float v = acc[mt][nt][r];
        if (MODE == 1) {
          const float e = (col <= row) ? __expf(v * 0.03125f) : 0.0f;  // s/sqrt(1024)
          rsum += e;
          v = e;
        } else if (MODE == 2) {
          v *= rinv;
        }
        Cw[(size_t)row * ldc + col] = (OT)v;
      }
      if (MODE == 1) {
        rsum += __shfl_xor(rsum, 1, 64);
        rsum += __shfl_xor(rsum, 2, 64);
        rsum += __shfl_xor(rsum, 4, 64);
        rsum += __shfl_xor(rsum, 8, 64);
        if (ln16 == 0) atomicAdd(rs_b + row, rsum);
      }
    }
  }
}

// three fp32 [D][D] -> bf16 transposed, stacked [3D][D]; z selects source
__global__ __launch_bounds__(256)
void transpose_cvt3(const float* __restrict__ w0, const float* __restrict__ w1,
                    const float* __restrict__ w2, bf16_t* __restrict__ out, int D)
{
  const float* in = (blockIdx.z == 0) ? w0 : (blockIdx.z == 1) ? w1 : w2;
  bf16_t* o = out + (size_t)blockIdx.z * D * D;
  __shared__ float tile[32][33];
  const int c0 = blockIdx.x * 32, r0 = blockIdx.y * 32;
  const int tx = threadIdx.x, ty = threadIdx.y;  // (32, 8)
#pragma unroll
  for (int i = 0; i < 32; i += 8)
    tile[ty + i][tx] = in[(size_t)(r0 + ty + i) * D + (c0 + tx)];
  __syncthreads();
#pragma unroll
  for (int i = 0; i < 32; i += 8)
    o[(size_t)(c0 + ty + i) * D + (r0 + tx)] = (bf16_t)tile[tx][ty + i];
}

// bf16 [R][C] -> bf16 transposed [C][R]; batched via blockIdx.z.
// Block (0,0,0) additionally zeroes the rowsum buffer (disjoint memory; its only
// consumer is the subsequent scores launch on the same stream).
__global__ __launch_bounds__(256)
void transpose16z(const unsigned short* __restrict__ in, unsigned short* __restrict__ out,
                  int R, int C, float* __restrict__ z, int nz)
{
  __shared__ unsigned short tile[32][33];
  const size_t bo = (size_t)blockIdx.z * R * C;
  const int c0 = blockIdx.x * 32, r0 = blockIdx.y * 32;
  const int tx = threadIdx.x, ty = threadIdx.y;  // (32, 8)
  if (blockIdx.x == 0 && blockIdx.y == 0 && blockIdx.z == 0) {
    const int t = ty * 32 + tx;
    for (int i = t; i < nz; i += 256) z[i] = 0.0f;
  }
#pragma unroll
  for (int i = 0; i < 32; i += 8)
    tile[ty + i][tx] = in[bo + (size_t)(r0 + ty + i) * C + (c0 + tx)];
  __syncthreads();
#pragma unroll
  for (int i = 0; i < 32; i += 8)
    out[bo + (size_t)(c0 + ty + i) * R + (r0 + tx)] = tile[tx][ty + i];
}

// fp32 -> bf16 elementwise, 8/thread, vector load+store
__global__ __launch_bounds__(256)
void cvt_f32_bf16(const float* __restrict__ in, bf16_t* __restrict__ out, long n)
{
  long i = ((long)blockIdx.x * 256 + threadIdx.x) * 8;
  if (i + 7 < n) {
    float4 a = *(const float4*)(in + i);
    float4 b = *(const float4*)(in + i + 4);
    bf16x8 o;
    o[0] = (bf16_t)a.x; o[1] = (bf16_t)a.y; o[2] = (bf16_t)a.z; o[3] = (bf16_t)a.w;
    o[4] = (bf16_t)b.x; o[5] = (bf16_t)b.y; o[6] = (bf16_t)b.z; o[7] = (bf16_t)b.w;
    *(bf16x8*)(out + i) = o;
  }
}

extern "C" void kernel_launch(void* const* d_in, const int* in_sizes, int n_in,
                              void* d_out, int out_size, void* d_ws, size_t ws_size,
                              hipStream_t stream) {
  const float* x  = (const float*)d_in[0];
  const float* Wq = (const float*)d_in[1];
  const float* Wk = (const float*)d_in[2];
  const float* Wv = (const float*)d_in[3];
  float* out = (float*)d_out;

  const int Bb = 4, S = 2048, D = 1024;
  const int M = Bb * S;  // 8192

  // ws (bf16 elems): Q | K | Vt | Wt(3*D*D) | Xb | V   = 90,177,536 B (proven fit)
  // Sc (Bb*S*S == 2*M*D) aliases [Xb|V]; rowsum (32 KB f32) reuses Wt (dead post-QKV).
  bf16_t* ws = (bf16_t*)d_ws;
  bf16_t* Q   = ws;
  bf16_t* Kp  = Q  + (size_t)M * D;
  bf16_t* Vt  = Kp + (size_t)M * D;
  bf16_t* Wt  = Vt + (size_t)M * D;          // [3072][1024] stacked
  bf16_t* Xb  = Wt + 3 * (size_t)D * D;
  bf16_t* V   = Xb + (size_t)M * D;
  bf16_t* Sc  = Xb;
  float*  rowsum = (float*)Wt;               // Bb*S floats

  const dim3 tb(32, 8);

  // 1) W fp32 -> bf16 transposed, stacked
  transpose_cvt3<<<dim3(D / 32, D / 32, 3), tb, 0, stream>>>(Wq, Wk, Wv, Wt, D);

  // 2) x -> bf16
  cvt_f32_bf16<<<dim3((M * D) / (256 * 8)), dim3(256), 0, stream>>>(x, Xb, (long)M * D);

  // 3) fused projections: {Q,K,V} = Xb * Wt^T  (128^2; grid 24x64 = 1536 = 6.0 rounds;
  //    measured 64.6-65.2 us across R12/R13)
  gemm_nt_bf16<128, 128, 4, 3, bf16_t><<<dim3(3 * D / 128, M / 128, 1), dim3(256), 0, stream>>>(
      Xb, Wt, Q, Kp, V, rowsum, M, D, D, 0, 0, 0);

  // 4) Vt per batch + zero rowsum (Wt dead now; fused into one dispatch)
  transpose16z<<<dim3(D / 32, S / 32, Bb), tb, 0, stream>>>(
      (const unsigned short*)V, (unsigned short*)Vt, S, D, rowsum, M);

  // 5) E = masked-exp(Q*K^T/32) + rowsum  (flat triangular grid: 544 tiles, 68/XCD exact)
  gemm_nt_bf16<128, 128, 4, 1, bf16_t><<<dim3(544, 1, 1), dim3(256), 0, stream>>>(
      Q, Kp, Sc, Sc, Sc, rowsum, S, D, S, (long)S * D, (long)S * D, (long)S * S);

  // 6) out(fp32) = (E*V)/rowsum  (panel-pinned flat grid: 512 blocks, 68 K-units/XCD)
  gemm_nt_bf16<128, 128, 4, 2, float><<<dim3(512, 1, 1), dim3(256), 0, stream>>>(
      Sc, Vt, out, out, out, rowsum, S, S, D, (long)S * S, (long)D * S, (long)S * D);
}

// Round 8
// 223.802 us; speedup vs baseline: 1.1257x; 1.0620x over previous
//
#include <hip/hip_runtime.h>
#include <hip/hip_bf16.h>

// CausalAttention: B=4, S=2048, d=1024, single head, causal. fp32 I/O, bf16 MFMA inside.
//
// R16: delete-work round. Accounting: movement kernels ~50 us (= scores+PV combined);
//      total pinned at ~237 across R12-R15 while GEMM maps were shuffled.
//      (a) QKV epilogue writes the V-third TRANSPOSED directly into Vt
//          (Vt[b][e][s]; 2B scattered stores, but each 64B line fully covered within
//          one block -> L2-merged). Deletes transpose16z (67 MB, ~22 us) + a dispatch.
//      (b) rowsum computed IN PV via ones-MFMA: acc_rs[mt] += mfma(af[mt], ones)
//          gives Sum_k E[row][k] in the exact epilogue C/D layout (+8 MFMA/K-step on a
//          14%-MfmaUtil kernel). Above-diagonal E entries are stored zeros -> exact.
//          Deletes scores' shfl+atomicAdd epilogue, the rowsum buffer and its zeroing,
//          and the scores->rowsum dependency. Denominator now sums bf16-rounded E
//          (tiny numerics shift vs fp32-pre-rounding sum).
//      GEMM K-loop/staging untouched (R9-R11 lesson). 5 dispatches total.
//
// Pipeline:
//   1) Wq/Wk/Wv fp32 -> bf16 transposed, stacked Wt [3072][1024]
//   2) x fp32 -> bf16 Xb
//   3) {Q,K,Vt} = Xb * Wt^T      (MODE 3, 128^2, grid 24x64; V written transposed)
//   4) E = masked-exp(Q*K^T/32)  (MODE 1, 128^2, flat tri grid 544; no rowsum)
//   5) out = (E*V) / (E*ones)    (MODE 2, 128^2, panel-pinned 512; rowsum via MFMA)

typedef __bf16 bf16_t;
typedef __bf16 bf16x8 __attribute__((ext_vector_type(8)));
typedef float f32x4 __attribute__((ext_vector_type(4)));

__device__ __forceinline__ void load_lds16(const bf16_t* g, bf16_t* l) {
  __builtin_amdgcn_global_load_lds(
      (__attribute__((address_space(1))) void*)(void*)g,
      (__attribute__((address_space(3))) void*)l,
      16, 0, 0);
}

// C[m][n] = sum_k A[m][k]*B[n][k]  (A:[M][K], B:[N][K] row-major bf16)
// MODE: 1 scores: flat triangular grid, epilogue mask+exp (no rowsum)
//       2 pv: panel-pinned flat grid, K clamped, rowsum via ones-MFMA, epilogue 1/rs
//       3 fused qkv split; V-third written transposed into Vt
// LDS swizzle: 16B chunk position p of row r holds global chunk p ^ (r&7);
// fragment reads hit all 32 banks 2-way (free, m136). Conflicts measured 0 (R5-R15).
template <int BMv, int BNv, int NW, int MODE, typename OT>
__global__ __launch_bounds__(NW * 64)
void gemm_nt_bf16(const bf16_t* __restrict__ A, const bf16_t* __restrict__ B,
                  OT* __restrict__ C0, OT* __restrict__ C1, OT* __restrict__ C2,
                  int M, int K, int ldc,
                  long strideA, long strideB, long strideC)
{
  constexpr int MW = BMv / 64;       // wave grid: MW x (NW/MW)
  constexpr int RA = BMv / NW;       // rows staged per wave (A)
  constexpr int RB = BNv / NW;       // rows staged per wave (B)

  int bx, by, bz;
  if constexpr (MODE == 1) {
    // Flat XCD-balanced lower-triangle enumeration (S=2048, 128-tiles, 16 panels/batch).
    // XCD x (= blockIdx.x & 7, m09 round-robin) owns panels {x, 15-x} of every batch:
    // weight (x+1) + (16-x) = 17 tiles per batch -> 68 per XCD, exact balance.
    const int f = blockIdx.x;          // 544 blocks
    const int x = f & 7;
    const int j = f >> 3;              // [0, 68)
    bz = j / 17;
    const int r = j % 17;
    by = (r <= x) ? x : 15 - x;
    bx = (r <= x) ? r : r - (x + 1);
  } else if constexpr (MODE == 2) {
    // PV panel-pinned flat grid: 512 blocks. XCD = f&7 owns 8 E row-panels
    // (4 heavy-first pairs; (16-pr)+(pr+1)=17 -> 68 K-units per XCD exactly).
    // bx fastest: the 8 col-blocks of a panel are consecutive ON ONE XCD -> A-panel
    // fetched once, ~2.2 MB/XCD in L2 (R14: 78 MB FETCH with the un-pinned map).
    const int f  = blockIdx.x;
    const int xcd = f & 7;
    const int i  = f >> 3;             // [0,64) within XCD
    bx = i & 7;
    const int p  = i >> 3;             // [0,8) panel slot
    const int j  = p & 3;              // pair index
    const int heavy = (p < 4);         // heavy panels first
    const int g  = xcd * 4 + j;        // [0,32) global (bz,pr) pair
    bz = g >> 3;
    const int pr = g & 7;
    by = heavy ? (15 - pr) : pr;
  } else {
    // XCD-aware remap: pin all x-blocks of an A-panel (y,z) to one XCD.
    // Requires (gridDim.y*gridDim.z) % 8 == 0 -- true here (64).
    const int gx = gridDim.x, gy = gridDim.y;
    const int NP = gy * gridDim.z;
    const int P  = NP >> 3;                         // panels per XCD
    const int flat = blockIdx.x + gx * (blockIdx.y + gy * blockIdx.z);
    const int xcd  = flat & 7;
    const int i    = flat >> 3;
    const int pan  = xcd * P + (i % P);
    bx = i / P;
    by = pan % gy;
    bz = pan / gy;
  }

  const int rowBase = by * BMv;
  const int colBase = bx * BNv;

  __shared__ __align__(16) bf16_t sA[BMv * 64];
  __shared__ __align__(16) bf16_t sB[BNv * 64];

  A += (size_t)bz * strideA;
  B += (size_t)bz * strideB;

  const int tid  = threadIdx.x;
  const int wave = tid >> 6;
  const int lane = tid & 63;
  const int quad = lane >> 4;
  const int ln16 = lane & 15;

  const int wm = (wave % MW) * 64;
  const int wn = (wave / MW) * 64;

  const int rA = lane >> 3;                       // 0..7 row-in-group
  const int sColOff = ((lane & 7) ^ rA) * 8;      // swizzled chunk offset (elems)
  const bf16_t* pA = A + (size_t)(rowBase + wave * RA + rA) * K + sColOff;
  const bf16_t* pB = B + (size_t)(colBase + wave * RB + rA) * K + sColOff;
  bf16_t* ldsA = sA + wave * RA * 64;
  bf16_t* ldsB = sB + wave * RB * 64;

  f32x4 acc[4][4] = {};
  f32x4 acc_rs[4] = {};                           // MODE 2: per-row E sums (ones-MFMA)
  bf16x8 ones;
#pragma unroll
  for (int i = 0; i < 8; i++) ones[i] = (bf16_t)1.0f;

  const int Kend = (MODE == 2) ? (K < rowBase + BMv ? K : rowBase + BMv) : K;

  for (int k0 = 0; k0 < Kend; k0 += 64) {
#pragma unroll
    for (int j = 0; j < RA / 8; j++)
      load_lds16(pA + k0 + (size_t)(8 * j) * K, ldsA + j * 512);
#pragma unroll
    for (int j = 0; j < RB / 8; j++)
      load_lds16(pB + k0 + (size_t)(8 * j) * K, ldsB + j * 512);
    __syncthreads();   // drains vmcnt for all waves

#pragma unroll
    for (int kk = 0; kk < 2; kk++) {
      bf16x8 af[4], bfr[4];
#pragma unroll
      for (int mt = 0; mt < 4; mt++) {
        const int row = wm + mt * 16 + ln16;
        af[mt] = *(const bf16x8*)(sA + row * 64 + (((kk * 4 + quad) ^ (row & 7)) * 8));
      }
#pragma unroll
      for (int nt = 0; nt < 4; nt++) {
        const int row = wn + nt * 16 + ln16;
        bfr[nt] = *(const bf16x8*)(sB + row * 64 + (((kk * 4 + quad) ^ (row & 7)) * 8));
      }
#pragma unroll
      for (int mt = 0; mt < 4; mt++) {
#pragma unroll
        for (int nt = 0; nt < 4; nt++)
          acc[mt][nt] = __builtin_amdgcn_mfma_f32_16x16x32_bf16(af[mt], bfr[nt], acc[mt][nt], 0, 0, 0);
        if constexpr (MODE == 2)
          acc_rs[mt] = __builtin_amdgcn_mfma_f32_16x16x32_bf16(af[mt], ones, acc_rs[mt], 0, 0, 0);
      }
    }
    __syncthreads();
  }

  // epilogue: C/D layout col = lane&15, row = quad*4 + r  [measured m89/m91]
  if constexpr (MODE == 3) {
    const int which = colBase >> 10;               // 128-col tiles never span matrices
    const int cb = colBase & 1023;
    if (which == 2) {
      // V-third: write transposed into Vt[b][e][s]  (b=row>>11, e=col, s=row&2047).
      // Each block covers 128 contiguous s per e-row -> 64B lines fully written
      // within one block/XCD -> L2 write-merge keeps HBM traffic at 33.5 MB.
#pragma unroll
      for (int mt = 0; mt < 4; mt++) {
#pragma unroll
        for (int r = 0; r < 4; r++) {
          const int row = rowBase + wm + mt * 16 + quad * 4 + r;
          const size_t vb = (size_t)(row >> 11) * (1024 * 2048) + (row & 2047);
#pragma unroll
          for (int nt = 0; nt < 4; nt++) {
            const int col = cb + wn + nt * 16 + ln16;
            C2[vb + (size_t)col * 2048] = (OT)acc[mt][nt][r];
          }
        }
      }
    } else {
      OT* Cw = which ? C1 : C0;
#pragma unroll
      for (int mt = 0; mt < 4; mt++) {
#pragma unroll
        for (int r = 0; r < 4; r++) {
          const int row = rowBase + wm + mt * 16 + quad * 4 + r;
#pragma unroll
          for (int nt = 0; nt < 4; nt++) {
            const int col = cb + wn + nt * 16 + ln16;
            Cw[(size_t)row * ldc + col] = (OT)acc[mt][nt][r];
          }
        }
      }
    }
    return;
  }

  OT* Cw = C0 + (size_t)bz * strideC;
#pragma unroll
  for (int mt = 0; mt < 4; mt++) {
#pragma unroll
    for (int r = 0; r < 4; r++) {
      const int row = rowBase + wm + mt * 16 + quad * 4 + r;
      const float rinv = (MODE == 2) ? 1.0f / acc_rs[mt][r] : 1.0f;
#pragma unroll
      for (int nt = 0; nt < 4; nt++) {
        const int col = colBase + wn + nt * 16 + ln16;
        float v = acc[mt][nt][r];
        if constexpr (MODE == 1) {
          v = (col <= row) ? __expf(v * 0.03125f) : 0.0f;   // s/sqrt(1024)
        } else {
          v *= rinv;
        }
        Cw[(size_t)row * ldc + col] = (OT)v;
      }
    }
  }
}

// three fp32 [D][D] -> bf16 transposed, stacked [3D][D]; z selects source
__global__ __launch_bounds__(256)
void transpose_cvt3(const float* __restrict__ w0, const float* __restrict__ w1,
                    const float* __restrict__ w2, bf16_t* __restrict__ out, int D)
{
  const float* in = (blockIdx.z == 0) ? w0 : (blockIdx.z == 1) ? w1 : w2;
  bf16_t* o = out + (size_t)blockIdx.z * D * D;
  __shared__ float tile[32][33];
  const int c0 = blockIdx.x * 32, r0 = blockIdx.y * 32;
  const int tx = threadIdx.x, ty = threadIdx.y;  // (32, 8)
#pragma unroll
  for (int i = 0; i < 32; i += 8)
    tile[ty + i][tx] = in[(size_t)(r0 + ty + i) * D + (c0 + tx)];
  __syncthreads();
#pragma unroll
  for (int i = 0; i < 32; i += 8)
    o[(size_t)(c0 + ty + i) * D + (r0 + tx)] = (bf16_t)tile[tx][ty + i];
}

// fp32 -> bf16 elementwise, 8/thread, vector load+store
__global__ __launch_bounds__(256)
void cvt_f32_bf16(const float* __restrict__ in, bf16_t* __restrict__ out, long n)
{
  long i = ((long)blockIdx.x * 256 + threadIdx.x) * 8;
  if (i + 7 < n) {
    float4 a = *(const float4*)(in + i);
    float4 b = *(const float4*)(in + i + 4);
    bf16x8 o;
    o[0] = (bf16_t)a.x; o[1] = (bf16_t)a.y; o[2] = (bf16_t)a.z; o[3] = (bf16_t)a.w;
    o[4] = (bf16_t)b.x; o[5] = (bf16_t)b.y; o[6] = (bf16_t)b.z; o[7] = (bf16_t)b.w;
    *(bf16x8*)(out + i) = o;
  }
}

extern "C" void kernel_launch(void* const* d_in, const int* in_sizes, int n_in,
                              void* d_out, int out_size, void* d_ws, size_t ws_size,
                              hipStream_t stream) {
  const float* x  = (const float*)d_in[0];
  const float* Wq = (const float*)d_in[1];
  const float* Wk = (const float*)d_in[2];
  const float* Wv = (const float*)d_in[3];
  float* out = (float*)d_out;

  const int Bb = 4, S = 2048, D = 1024;
  const int M = Bb * S;  // 8192

  // ws (bf16 elems): Q | K | Vt | Wt(3*D*D) | Xb | (V: dead, part of Sc)
  // Sc (Bb*S*S == 2*M*D) aliases [Xb | old-V region]. No rowsum buffer anymore.
  bf16_t* ws = (bf16_t*)d_ws;
  bf16_t* Q   = ws;
  bf16_t* Kp  = Q  + (size_t)M * D;
  bf16_t* Vt  = Kp + (size_t)M * D;
  bf16_t* Wt  = Vt + (size_t)M * D;          // [3072][1024] stacked
  bf16_t* Xb  = Wt + 3 * (size_t)D * D;
  bf16_t* Sc  = Xb;

  const dim3 tb(32, 8);

  // 1) W fp32 -> bf16 transposed, stacked
  transpose_cvt3<<<dim3(D / 32, D / 32, 3), tb, 0, stream>>>(Wq, Wk, Wv, Wt, D);

  // 2) x -> bf16
  cvt_f32_bf16<<<dim3((M * D) / (256 * 8)), dim3(256), 0, stream>>>(x, Xb, (long)M * D);

  // 3) fused projections: {Q,K,Vt} = Xb * Wt^T  (V written transposed directly)
  gemm_nt_bf16<128, 128, 4, 3, bf16_t><<<dim3(3 * D / 128, M / 128, 1), dim3(256), 0, stream>>>(
      Xb, Wt, Q, Kp, Vt, M, D, D, 0, 0, 0);

  // 4) E = masked-exp(Q*K^T/32)  (flat triangular grid: 544 tiles, 68/XCD exact)
  gemm_nt_bf16<128, 128, 4, 1, bf16_t><<<dim3(544, 1, 1), dim3(256), 0, stream>>>(
      Q, Kp, Sc, Sc, Sc, S, D, S, (long)S * D, (long)S * D, (long)S * S);

  // 5) out = (E*V) / (E*ones)  (panel-pinned flat grid: 512 blocks, 68 K-units/XCD)
  gemm_nt_bf16<128, 128, 4, 2, float><<<dim3(512, 1, 1), dim3(256), 0, stream>>>(
      Sc, Vt, out, out, out, S, S, D, (long)S * S, (long)D * S, (long)S * D);
}